// Round 10
// baseline (145.583 us; speedup 1.0000x reference)
//
#include <hip/hip_runtime.h>

#define N_ROWS 8192
#define DIM 256
#define NUM_CLASSES 64
#define NBLK 64                        // 8192/128 row/col blocks
#define NTRI (NBLK * (NBLK + 1) / 2)   // 2080 upper-triangle tiles
#define SCR_PITCH 36                   // 32 data + pad; 144B row stride

typedef float f32x4 __attribute__((ext_vector_type(4)));

__device__ __forceinline__ void gload_lds16(const void* g, void* l) {
  __builtin_amdgcn_global_load_lds(
      (const __attribute__((address_space(1))) unsigned int*)g,
      (__attribute__((address_space(3))) unsigned int*)l, 16, 0, 0);
}

__device__ __forceinline__ void tri_decode(int q, int& I, int& J) {
  int i = (int)((129.0f - sqrtf(16641.0f - 8.0f * (float)q)) * 0.5f);
  while (i * (129 - i) / 2 > q) --i;
  while ((i + 1) * (128 - i) / 2 <= q) ++i;
  I = i;
  J = i + (q - i * (129 - i) / 2);
}

// Kernel 1: fp8 e4m3 quantize (HW cvt), per-row sum-of-squares of the
// *quantized* values (diagonal cos exact), s_i = sqrt((log2e/t)/ss).
// Blocks 0..31: sliced label histogram (LDS, contention-free). Block 0
// zeroes gsum/gcnt/arrive for main's fused finalize.
__global__ void __launch_bounds__(256) prep_kernel(
    const float* __restrict__ x, const int* __restrict__ lab,
    const float* __restrict__ tptr, unsigned int* __restrict__ xq,
    float* __restrict__ sv, int* __restrict__ hpart,
    unsigned int* __restrict__ arrive, float* __restrict__ gsum,
    unsigned int* __restrict__ gcnt) {
  const int tid = threadIdx.x;
  const int row = blockIdx.x * 4 + (tid >> 6);
  const int lane = tid & 63;
  const float4 v = *reinterpret_cast<const float4*>(x + (size_t)row * DIM + lane * 4);
  int p = __builtin_amdgcn_cvt_pk_fp8_f32(v.x, v.y, 0, false);   // bytes 0,1
  p = __builtin_amdgcn_cvt_pk_fp8_f32(v.z, v.w, p, true);        // bytes 2,3
  const float f0 = __builtin_amdgcn_cvt_f32_fp8(p, 0);
  const float f1 = __builtin_amdgcn_cvt_f32_fp8(p, 1);
  const float f2 = __builtin_amdgcn_cvt_f32_fp8(p, 2);
  const float f3 = __builtin_amdgcn_cvt_f32_fp8(p, 3);
  float ss = f0 * f0 + f1 * f1 + f2 * f2 + f3 * f3;
  xq[(size_t)row * 64 + lane] = (unsigned int)p;
  for (int m = 32; m; m >>= 1) ss += __shfl_xor(ss, m, 64);
  if (lane == 0) sv[row] = sqrtf(1.4426950408889634f / tptr[0] / ss);

  if (blockIdx.x < 32) {  // sliced histogram: 256 labels/block, LDS atomics only
    __shared__ int h[NUM_CLASSES];
    if (tid < NUM_CLASSES) h[tid] = 0;
    __syncthreads();
    atomicAdd(&h[lab[blockIdx.x * 256 + tid]], 1);
    __syncthreads();
    if (tid < NUM_CLASSES) hpart[blockIdx.x * NUM_CLASSES + tid] = h[tid];
  }
  if (blockIdx.x == 0) {
    for (int i = tid; i < NBLK * 16; i += 256) arrive[i] = 0u;
    if (tid == 0) { *gsum = 0.f; *gcnt = 0u; }
  }
}

// Finalize one rowblock R: sum its 64 part slots per row, per-row loss term,
// block-reduce, device-scope accumulate; last rowblock writes the scalar.
__device__ __forceinline__ void finalize_rowblock(
    int R, const float2* __restrict__ part, const int* __restrict__ lab,
    const int* __restrict__ hpart, float* __restrict__ gsum,
    unsigned int* __restrict__ gcnt, float* __restrict__ out, int tid,
    int* cls, float* fred) {
  if (tid < NUM_CLASSES) {
    int s = 0;
#pragma unroll
    for (int k = 0; k < 32; ++k) s += hpart[k * NUM_CLASSES + tid];
    cls[tid] = s;
  }
  __syncthreads();
  float term = 0.f;
  if (tid < 128) {
    const int row = R * 128 + tid;
    float st = 0.f, sm = 0.f;
#pragma unroll 8
    for (int b = 0; b < 64; ++b) {
      const float2 v = part[(size_t)b * N_ROWS + row];
      st += v.x;
      sm += v.y;
    }
    const int c = cls[lab[row]];
    const float pos = sm + (float)(N_ROWS - c);
    const float neg = (st - sm) + (float)c;
    term = logf(neg) - logf(pos);
  }
  for (int m = 32; m; m >>= 1) term += __shfl_xor(term, m, 64);
  if (tid < 128 && (tid & 63) == 0) fred[tid >> 6] = term;
  __syncthreads();
  if (tid == 0) {
    atomicAdd(gsum, fred[0] + fred[1]);
    __threadfence();
    const unsigned int t = atomicAdd(gcnt, 1u);
    if (t == (unsigned int)(NBLK - 1)) {          // last rowblock finished
      out[0] = atomicAdd(gsum, 0.0f) * (1.0f / (float)N_ROWS);
    }
  }
  __syncthreads();  // protect cls/fred reuse by a second finalize
}

// Kernel 2: upper-triangle 128x128 Gram tiles, fp8 MFMA 16x16x32, K-split
// staging (LDS 41KB -> 3 blocks/CU), swizzled ds_read_b64, exp2 epilogue,
// padded-LDS row reduction, float2 partials — PLUS fused last-arrival
// finalize per rowblock (replaces the row_loss kernel entirely).
__global__ void __launch_bounds__(256, 3) main_kernel(
    const unsigned char* __restrict__ xb, const float* __restrict__ sv,
    const int* __restrict__ lab, float2* __restrict__ part,
    const int* __restrict__ hpart, unsigned int* __restrict__ arrive,
    float* __restrict__ gsum, unsigned int* __restrict__ gcnt,
    float* __restrict__ out) {
  const int q = blockIdx.x;
  int I, J;
  tri_decode(q, I, J);
  const int rowBase = I * 128;
  const int colBase = J * 128;

  __shared__ alignas(16) unsigned char buf[36864];  // staging 32KB; scr alias
  __shared__ float colred[2][128][2];
  __shared__ float rsv[128]; __shared__ int rlab[128];
  __shared__ float csv[128]; __shared__ int clab[128];
  __shared__ int cls[NUM_CLASSES];
  __shared__ float fred[2];
  __shared__ int doneA, doneB;
  unsigned char* Al = buf;            // 128 rows x 128 B (one K half)
  unsigned char* Bl = buf + 16384;
  float* scr0 = reinterpret_cast<float*>(buf);           // 18432 B
  float* scr1 = reinterpret_cast<float*>(buf + 18432);   // 18432 B

  const int tid = threadIdx.x;
  const int wave = tid >> 6;
  const int lane = tid & 63;
  const int quad = lane >> 4;
  const int lc = lane & 15;
  const int wrow = (wave >> 1) * 64;
  const int wcol = (wave & 1) * 64;
  const int ch = wave & 1;
  const int r8 = lane >> 3;      // staging: 8 rows per instruction
  const int c8 = lane & 7;       // 8 x 16B chunks per half-row

  if (tid < 128) {
    rsv[tid] = sv[rowBase + tid];
    rlab[tid] = lab[rowBase + tid];
    csv[tid] = sv[colBase + tid];
    clab[tid] = lab[colBase + tid];
  }

  const unsigned char* Ag = xb + (size_t)rowBase * DIM;
  const unsigned char* Bg = xb + (size_t)colBase * DIM;

  // stage one K-half of A and B: LDS (r,c) <- global (r, h*128 + (c^(r&7))*16)
#define STAGE_HALF(h)                                                         \
  {                                                                           \
    _Pragma("unroll") for (int i = 0; i < 4; ++i) {                           \
      const int r = wave * 32 + i * 8 + r8;                                   \
      const int gc = c8 ^ (r & 7);                                            \
      gload_lds16(Ag + (size_t)r * 256 + (h)*128 + gc * 16,                   \
                  Al + (wave * 32 + i * 8) * 128);                            \
      gload_lds16(Bg + (size_t)r * 256 + (h)*128 + gc * 16,                   \
                  Bl + (wave * 32 + i * 8) * 128);                            \
    }                                                                         \
  }

  f32x4 acc[4][4];
  const f32x4 zero4 = {0.f, 0.f, 0.f, 0.f};
  for (int mi = 0; mi < 4; ++mi)
    for (int ni = 0; ni < 4; ++ni) acc[mi][ni] = zero4;

  const int qh = quad >> 1, h8 = (quad & 1) * 8;
  int aOff[4], bOff[4];
#pragma unroll
  for (int mi = 0; mi < 4; ++mi)
    aOff[mi] = (wrow + mi * 16 + lc) * 128 + h8;
#pragma unroll
  for (int ni = 0; ni < 4; ++ni)
    bOff[ni] = (wcol + ni * 16 + lc) * 128 + h8;

  STAGE_HALF(0)
  __syncthreads();  // half-0 staged
#pragma unroll
  for (int half = 0; half < 2; ++half) {
#pragma unroll
    for (int kbl = 0; kbl < 4; ++kbl) {
      const int swz = (((kbl * 2 + qh) ^ (lc & 7)) << 4);
      long afr[4], bfr[4];
#pragma unroll
      for (int mi = 0; mi < 4; ++mi)
        afr[mi] = *reinterpret_cast<const long*>(Al + aOff[mi] + swz);
#pragma unroll
      for (int ni = 0; ni < 4; ++ni)
        bfr[ni] = *reinterpret_cast<const long*>(Bl + bOff[ni] + swz);
#pragma unroll
      for (int mi = 0; mi < 4; ++mi)
#pragma unroll
        for (int ni = 0; ni < 4; ++ni)
          acc[mi][ni] = __builtin_amdgcn_mfma_f32_16x16x32_fp8_fp8(
              afr[mi], bfr[ni], acc[mi][ni], 0, 0, 0);
    }
    __syncthreads();  // readers done with this half
    if (half == 0) {
      STAGE_HALF(1)
      __syncthreads();  // half-1 staged
    }
  }
#undef STAGE_HALF

  // ---- epilogue (buf now reusable as scratch) ----
  float scol[4];
  int labc[4];
#pragma unroll
  for (int ni = 0; ni < 4; ++ni) {
    scol[ni] = csv[wcol + ni * 16 + lc];
    labc[ni] = clab[wcol + ni * 16 + lc];
  }
  float ctot[4] = {0.f, 0.f, 0.f, 0.f};
  float csame[4] = {0.f, 0.f, 0.f, 0.f};

#pragma unroll
  for (int mi = 0; mi < 4; ++mi) {
#pragma unroll
    for (int r = 0; r < 4; ++r) {
      const int lr = wrow + mi * 16 + quad * 4 + r;  // C/D: row=(lane>>4)*4+reg
      const float siv = rsv[lr];
      const int li = rlab[lr];
      float st = 0.f, sm = 0.f;
#pragma unroll
      for (int ni = 0; ni < 4; ++ni) {
        const float e = exp2f(acc[mi][ni][r] * (siv * scol[ni]));
        const float em = (li == labc[ni]) ? e : 0.f;
        st += e;
        sm += em;
        ctot[ni] += e;
        csame[ni] += em;
      }
      scr0[lr * SCR_PITCH + ch * 16 + lc] = st;
      scr1[lr * SCR_PITCH + ch * 16 + lc] = sm;
    }
  }

  if (J > I) {
#pragma unroll
    for (int ni = 0; ni < 4; ++ni) {
      float t2 = ctot[ni] + __shfl_xor(ctot[ni], 16, 64);
      t2 += __shfl_xor(t2, 32, 64);
      float s2 = csame[ni] + __shfl_xor(csame[ni], 16, 64);
      s2 += __shfl_xor(s2, 32, 64);
      if (quad == 0) {
        colred[0][wcol + ni * 16 + lc][wave >> 1] = t2;
        colred[1][wcol + ni * 16 + lc][wave >> 1] = s2;
      }
    }
  }
  __syncthreads();

  if (tid < 128) {
    const int base = tid * SCR_PITCH;
    f32x4 a0 = {0.f, 0.f, 0.f, 0.f}, a1 = {0.f, 0.f, 0.f, 0.f};
#pragma unroll
    for (int k = 0; k < 8; ++k)
      a0 += *reinterpret_cast<const f32x4*>(&scr0[base + 4 * k]);
#pragma unroll
    for (int k = 0; k < 8; ++k)
      a1 += *reinterpret_cast<const f32x4*>(&scr1[base + 4 * k]);
    float2 v;
    v.x = a0[0] + a0[1] + a0[2] + a0[3];
    v.y = a1[0] + a1[1] + a1[2] + a1[3];
    part[(size_t)J * N_ROWS + rowBase + tid] = v;
    if (J > I) {
      float2 w;
      w.x = colred[0][tid][0] + colred[0][tid][1];
      w.y = colred[1][tid][0] + colred[1][tid][1];
      part[(size_t)I * N_ROWS + colBase + tid] = w;
    }
  }
  __syncthreads();  // all part stores issued (barrier drains vmcnt)

  // ---- last-arrival fused finalize ----
  if (tid == 0) {
    __threadfence();  // writeback to device scope before signaling
    doneA = (atomicAdd(&arrive[I * 16], 1u) == (unsigned int)(NBLK - 1));
    doneB = 0;
    if (J > I)
      doneB = (atomicAdd(&arrive[J * 16], 1u) == (unsigned int)(NBLK - 1));
  }
  __syncthreads();
  if (doneA)
    finalize_rowblock(I, part, lab, hpart, gsum, gcnt, out, tid, cls, fred);
  if (doneB)
    finalize_rowblock(J, part, lab, hpart, gsum, gcnt, out, tid, cls, fred);
}

extern "C" void kernel_launch(void* const* d_in, const int* in_sizes, int n_in,
                              void* d_out, int out_size, void* d_ws, size_t ws_size,
                              hipStream_t stream) {
  const float* x = (const float*)d_in[0];
  const int* lab = (const int*)d_in[1];
  const float* t = (const float*)d_in[2];
  float* out = (float*)d_out;

  char* ws = (char*)d_ws;
  unsigned int* xq = (unsigned int*)ws;                          // 2 MiB fp8 X
  float* sv = (float*)(ws + (2u << 20));                         // 32 KiB scales
  float2* part = (float2*)(ws + (2u << 20) + (32u << 10));       // 4 MiB partials
  float* gsum = (float*)(ws + (6u << 20) + (32u << 10));
  unsigned int* gcnt = (unsigned int*)(ws + (6u << 20) + (32u << 10) + 8);
  int* hpart = (int*)(ws + (6u << 20) + (33u << 10));            // 8 KiB
  unsigned int* arrive = (unsigned int*)(ws + (6u << 20) + (42u << 10)); // 4 KiB

  prep_kernel<<<N_ROWS / 4, 256, 0, stream>>>(x, lab, t, xq, sv, hpart, arrive,
                                              gsum, gcnt);
  main_kernel<<<NTRI, 256, 0, stream>>>((const unsigned char*)xq, sv, lab, part,
                                        hpart, arrive, gsum, gcnt, out);
}

// Round 11
// 96.054 us; speedup vs baseline: 1.5156x; 1.5156x over previous
//
#include <hip/hip_runtime.h>

#define N_ROWS 8192
#define DIM 256
#define NUM_CLASSES 64
#define NBLK 64                        // 8192/128 row/col blocks
#define NTRI (NBLK * (NBLK + 1) / 2)   // 2080 upper-triangle tiles
#define SCR_PITCH 36                   // 32 data + pad; 144B row stride

typedef float f32x4 __attribute__((ext_vector_type(4)));

__device__ __forceinline__ void gload_lds16(const void* g, void* l) {
  __builtin_amdgcn_global_load_lds(
      (const __attribute__((address_space(1))) unsigned int*)g,
      (__attribute__((address_space(3))) unsigned int*)l, 16, 0, 0);
}

__device__ __forceinline__ void tri_decode(int q, int& I, int& J) {
  int i = (int)((129.0f - sqrtf(16641.0f - 8.0f * (float)q)) * 0.5f);
  while (i * (129 - i) / 2 > q) --i;
  while ((i + 1) * (128 - i) / 2 <= q) ++i;
  I = i;
  J = i + (q - i * (129 - i) / 2);
}

// Kernel 1: fp8 e4m3 quantize (HW cvt), per-row sum-of-squares of the
// *quantized* values (diagonal cos exact), s_i = sqrt((log2e/t)/ss).
// Blocks 0..31 also build a sliced label histogram (LDS, contention-free).
// Block 0 zeroes gsum/gcnt.
__global__ void __launch_bounds__(256) prep_kernel(
    const float* __restrict__ x, const int* __restrict__ lab,
    const float* __restrict__ tptr, unsigned int* __restrict__ xq,
    float* __restrict__ sv, int* __restrict__ hpart,
    float* __restrict__ gsum, unsigned int* __restrict__ gcnt) {
  const int tid = threadIdx.x;
  if (blockIdx.x == 0 && tid == 0) { *gsum = 0.f; *gcnt = 0u; }
  const int row = blockIdx.x * 4 + (tid >> 6);
  const int lane = tid & 63;
  const float4 v = *reinterpret_cast<const float4*>(x + (size_t)row * DIM + lane * 4);
  int p = __builtin_amdgcn_cvt_pk_fp8_f32(v.x, v.y, 0, false);   // bytes 0,1
  p = __builtin_amdgcn_cvt_pk_fp8_f32(v.z, v.w, p, true);        // bytes 2,3
  const float f0 = __builtin_amdgcn_cvt_f32_fp8(p, 0);
  const float f1 = __builtin_amdgcn_cvt_f32_fp8(p, 1);
  const float f2 = __builtin_amdgcn_cvt_f32_fp8(p, 2);
  const float f3 = __builtin_amdgcn_cvt_f32_fp8(p, 3);
  float ss = f0 * f0 + f1 * f1 + f2 * f2 + f3 * f3;
  xq[(size_t)row * 64 + lane] = (unsigned int)p;
  for (int m = 32; m; m >>= 1) ss += __shfl_xor(ss, m, 64);
  if (lane == 0) sv[row] = sqrtf(1.4426950408889634f / tptr[0] / ss);

  if (blockIdx.x < 32) {  // sliced histogram: 256 labels/block, LDS atomics only
    __shared__ int h[NUM_CLASSES];
    if (tid < NUM_CLASSES) h[tid] = 0;
    __syncthreads();
    atomicAdd(&h[lab[blockIdx.x * 256 + tid]], 1);
    __syncthreads();
    if (tid < NUM_CLASSES) hpart[blockIdx.x * NUM_CLASSES + tid] = h[tid];
  }
}

// Kernel 2: upper-triangle 128x128 Gram tiles, fp8 MFMA 16x16x32. K-SPLIT
// staging: K half [0,128) of both tiles (16KB+16KB) staged, 4-kb compute,
// then half [128,256) into the same buffer. LDS ~41KB -> 3 blocks/CU.
// 16B chunks XOR-swizzled (c = s ^ (lc&7)) on the global source side.
// Epilogue: exp2 + padded-LDS row reduction; (S_tot,S_same) as float2.
// NO device-scope fences here (R10 lesson: per-block __threadfence() on
// non-coherent XCD L2s = per-tile cache drain, 3x regression).
__global__ void __launch_bounds__(256, 3) main_kernel(
    const unsigned char* __restrict__ xb, const float* __restrict__ sv,
    const int* __restrict__ lab, float2* __restrict__ part) {
  const int q = blockIdx.x;
  int I, J;
  tri_decode(q, I, J);
  const int rowBase = I * 128;
  const int colBase = J * 128;

  __shared__ alignas(16) unsigned char buf[36864];  // staging 32KB; scr alias
  __shared__ float colred[2][128][2];
  __shared__ float rsv[128]; __shared__ int rlab[128];
  __shared__ float csv[128]; __shared__ int clab[128];
  unsigned char* Al = buf;            // 128 rows x 128 B (one K half)
  unsigned char* Bl = buf + 16384;
  float* scr0 = reinterpret_cast<float*>(buf);           // 18432 B
  float* scr1 = reinterpret_cast<float*>(buf + 18432);   // 18432 B

  const int tid = threadIdx.x;
  const int wave = tid >> 6;
  const int lane = tid & 63;
  const int quad = lane >> 4;
  const int lc = lane & 15;
  const int wrow = (wave >> 1) * 64;
  const int wcol = (wave & 1) * 64;
  const int ch = wave & 1;
  const int r8 = lane >> 3;      // staging: 8 rows per instruction
  const int c8 = lane & 7;       // 8 x 16B chunks per half-row

  if (tid < 128) {
    rsv[tid] = sv[rowBase + tid];
    rlab[tid] = lab[rowBase + tid];
    csv[tid] = sv[colBase + tid];
    clab[tid] = lab[colBase + tid];
  }

  const unsigned char* Ag = xb + (size_t)rowBase * DIM;
  const unsigned char* Bg = xb + (size_t)colBase * DIM;

  // stage one K-half of A and B: LDS (r,c) <- global (r, h*128 + (c^(r&7))*16)
#define STAGE_HALF(h)                                                         \
  {                                                                           \
    _Pragma("unroll") for (int i = 0; i < 4; ++i) {                           \
      const int r = wave * 32 + i * 8 + r8;                                   \
      const int gc = c8 ^ (r & 7);                                            \
      gload_lds16(Ag + (size_t)r * 256 + (h)*128 + gc * 16,                   \
                  Al + (wave * 32 + i * 8) * 128);                            \
      gload_lds16(Bg + (size_t)r * 256 + (h)*128 + gc * 16,                   \
                  Bl + (wave * 32 + i * 8) * 128);                            \
    }                                                                         \
  }

  f32x4 acc[4][4];
  const f32x4 zero4 = {0.f, 0.f, 0.f, 0.f};
  for (int mi = 0; mi < 4; ++mi)
    for (int ni = 0; ni < 4; ++ni) acc[mi][ni] = zero4;

  const int qh = quad >> 1, h8 = (quad & 1) * 8;
  int aOff[4], bOff[4];
#pragma unroll
  for (int mi = 0; mi < 4; ++mi)
    aOff[mi] = (wrow + mi * 16 + lc) * 128 + h8;
#pragma unroll
  for (int ni = 0; ni < 4; ++ni)
    bOff[ni] = (wcol + ni * 16 + lc) * 128 + h8;

  STAGE_HALF(0)
  __syncthreads();  // half-0 staged
#pragma unroll
  for (int half = 0; half < 2; ++half) {
#pragma unroll
    for (int kbl = 0; kbl < 4; ++kbl) {
      const int swz = (((kbl * 2 + qh) ^ (lc & 7)) << 4);
      long afr[4], bfr[4];
#pragma unroll
      for (int mi = 0; mi < 4; ++mi)
        afr[mi] = *reinterpret_cast<const long*>(Al + aOff[mi] + swz);
#pragma unroll
      for (int ni = 0; ni < 4; ++ni)
        bfr[ni] = *reinterpret_cast<const long*>(Bl + bOff[ni] + swz);
#pragma unroll
      for (int mi = 0; mi < 4; ++mi)
#pragma unroll
        for (int ni = 0; ni < 4; ++ni)
          acc[mi][ni] = __builtin_amdgcn_mfma_f32_16x16x32_fp8_fp8(
              afr[mi], bfr[ni], acc[mi][ni], 0, 0, 0);
    }
    __syncthreads();  // readers done with this half
    if (half == 0) {
      STAGE_HALF(1)
      __syncthreads();  // half-1 staged
    }
  }
#undef STAGE_HALF

  // ---- epilogue (buf now reusable as scratch) ----
  float scol[4];
  int labc[4];
#pragma unroll
  for (int ni = 0; ni < 4; ++ni) {
    scol[ni] = csv[wcol + ni * 16 + lc];
    labc[ni] = clab[wcol + ni * 16 + lc];
  }
  float ctot[4] = {0.f, 0.f, 0.f, 0.f};
  float csame[4] = {0.f, 0.f, 0.f, 0.f};

#pragma unroll
  for (int mi = 0; mi < 4; ++mi) {
#pragma unroll
    for (int r = 0; r < 4; ++r) {
      const int lr = wrow + mi * 16 + quad * 4 + r;  // C/D: row=(lane>>4)*4+reg
      const float siv = rsv[lr];
      const int li = rlab[lr];
      float st = 0.f, sm = 0.f;
#pragma unroll
      for (int ni = 0; ni < 4; ++ni) {
        const float e = exp2f(acc[mi][ni][r] * (siv * scol[ni]));
        const float em = (li == labc[ni]) ? e : 0.f;
        st += e;
        sm += em;
        ctot[ni] += e;
        csame[ni] += em;
      }
      scr0[lr * SCR_PITCH + ch * 16 + lc] = st;
      scr1[lr * SCR_PITCH + ch * 16 + lc] = sm;
    }
  }

  if (J > I) {
#pragma unroll
    for (int ni = 0; ni < 4; ++ni) {
      float t2 = ctot[ni] + __shfl_xor(ctot[ni], 16, 64);
      t2 += __shfl_xor(t2, 32, 64);
      float s2 = csame[ni] + __shfl_xor(csame[ni], 16, 64);
      s2 += __shfl_xor(s2, 32, 64);
      if (quad == 0) {
        colred[0][wcol + ni * 16 + lc][wave >> 1] = t2;
        colred[1][wcol + ni * 16 + lc][wave >> 1] = s2;
      }
    }
  }
  __syncthreads();

  if (tid < 128) {
    const int base = tid * SCR_PITCH;
    f32x4 a0 = {0.f, 0.f, 0.f, 0.f}, a1 = {0.f, 0.f, 0.f, 0.f};
#pragma unroll
    for (int k = 0; k < 8; ++k)
      a0 += *reinterpret_cast<const f32x4*>(&scr0[base + 4 * k]);
#pragma unroll
    for (int k = 0; k < 8; ++k)
      a1 += *reinterpret_cast<const f32x4*>(&scr1[base + 4 * k]);
    float2 v;
    v.x = a0[0] + a0[1] + a0[2] + a0[3];
    v.y = a1[0] + a1[1] + a1[2] + a1[3];
    part[(size_t)J * N_ROWS + rowBase + tid] = v;
    if (J > I) {
      float2 w;
      w.x = colred[0][tid][0] + colred[0][tid][1];
      w.y = colred[1][tid][0] + colred[1][tid][1];
      part[(size_t)I * N_ROWS + colBase + tid] = w;
    }
  }
}

// Kernel 3: per-row loss terms; class counts from prep's sliced histogram
// (2048 int loads — no per-block 8192-label rebuild); device-scope finalize
// by last-arriving block (kernel-boundary ordering makes part[] visible).
__global__ void __launch_bounds__(256) row_loss_kernel(
    const float2* __restrict__ part, const int* __restrict__ lab,
    const int* __restrict__ hpart, float* __restrict__ gsum,
    unsigned int* __restrict__ gcnt, float* __restrict__ out) {
  __shared__ int h[NUM_CLASSES];
  if (threadIdx.x < NUM_CLASSES) {
    int s = 0;
#pragma unroll
    for (int k = 0; k < 32; ++k) s += hpart[k * NUM_CLASSES + threadIdx.x];
    h[threadIdx.x] = s;
  }
  __syncthreads();

  const int row = blockIdx.x * 256 + threadIdx.x;
  float st = 0.f, sm = 0.f;
#pragma unroll 8
  for (int b = 0; b < 64; ++b) {
    const float2 v = part[(size_t)b * N_ROWS + row];
    st += v.x;
    sm += v.y;
  }
  const int c = h[lab[row]];
  const float pos = sm + (float)(N_ROWS - c);
  const float neg = (st - sm) + (float)c;
  float term = logf(neg) - logf(pos);
  for (int m = 32; m; m >>= 1) term += __shfl_xor(term, m, 64);
  __shared__ float wsum[4];
  const int lane = threadIdx.x & 63;
  const int wave = threadIdx.x >> 6;
  if (lane == 0) wsum[wave] = term;
  __syncthreads();
  if (threadIdx.x == 0) {
    atomicAdd(gsum, wsum[0] + wsum[1] + wsum[2] + wsum[3]);
    __threadfence();
    const unsigned int t = atomicAdd(gcnt, 1u);
    if (t == (unsigned int)(N_ROWS / 256 - 1)) {  // last block
      const float total = atomicAdd(gsum, 0.0f);  // coherent read
      out[0] = total * (1.0f / (float)N_ROWS);
    }
  }
}

extern "C" void kernel_launch(void* const* d_in, const int* in_sizes, int n_in,
                              void* d_out, int out_size, void* d_ws, size_t ws_size,
                              hipStream_t stream) {
  const float* x = (const float*)d_in[0];
  const int* lab = (const int*)d_in[1];
  const float* t = (const float*)d_in[2];
  float* out = (float*)d_out;

  char* ws = (char*)d_ws;
  unsigned int* xq = (unsigned int*)ws;                          // 2 MiB fp8 X
  float* sv = (float*)(ws + (2u << 20));                         // 32 KiB scales
  float2* part = (float2*)(ws + (2u << 20) + (32u << 10));       // 4 MiB partials
  float* gsum = (float*)(ws + (6u << 20) + (32u << 10));
  unsigned int* gcnt = (unsigned int*)(ws + (6u << 20) + (32u << 10) + 8);
  int* hpart = (int*)(ws + (6u << 20) + (33u << 10));            // 8 KiB

  prep_kernel<<<N_ROWS / 4, 256, 0, stream>>>(x, lab, t, xq, sv, hpart, gsum, gcnt);
  main_kernel<<<NTRI, 256, 0, stream>>>((const unsigned char*)xq, sv, lab, part);
  row_loss_kernel<<<N_ROWS / 256, 256, 0, stream>>>(part, lab, hpart, gsum, gcnt, out);
}